// Round 1
// 165.973 us; speedup vs baseline: 1.0436x; 1.0436x over previous
//
#include <hip/hip_runtime.h>
#include <cstdint>
#include <cstddef>

#define N_TOKENS 65536
#define DIM 64
#define K_CODES 1024
#define NTH 256
#define NTHM 512                // vq_main threads (8 waves)
#define TPB 128                 // tokens per main block
#define NCH 16                  // chunks of 64 codes

// out layout (floats): [0]=loss, [1..4194304]=quantized, [4194305]=perplexity,
// [4194306..4259841]=indices
#define OFF_Q 1
#define OFF_PERP 4194305
#define OFF_IDX 4194306

// approx-vs-exact decision margin (worst-case error bound ~4.6e-5, 3.3x slack)
// main loop tracks m = acc = x.w - 0.5*s2 (max); d = -2*m exactly, so
// (d2-d1) < MARGIN  <=>  (m1-m2) < MARGIN/2  (x2 is exact, RN commutes with x2)
#define MARGIN 1.5e-4f
#define HMARGIN 7.5e-5f

// ws byte offsets
#define WS_LOSS   0        // double
#define WS_FCNT   8        // int
#define WS_COUNTS 16       // int[1024]
#define WS_WHI    4112     // ushort[65536], 16B aligned, MFMA-swizzled
#define WS_WLO    135184   // ushort[65536]
#define WS_S2     266256   // float[1024]
#define WS_FLIST  270352   // ushort[65536]

typedef __attribute__((ext_vector_type(8))) short  s16x8;
typedef __attribute__((ext_vector_type(4))) float  f32x4;

__device__ __forceinline__ float fmulr(float a, float b){ return __fmul_rn(a,b); }
__device__ __forceinline__ float faddr(float a, float b){ return __fadd_rn(a,b); }

__device__ __forceinline__ unsigned short f2bf(float f) {
    unsigned u = __float_as_uint(f);
    unsigned r = u + 0x7fffu + ((u >> 16) & 1u);   // RNE
    return (unsigned short)(r >> 16);
}
__device__ __forceinline__ float bf2f(unsigned short h) {
    return __uint_as_float(((unsigned)h) << 16);
}

// numpy (AVX512 pairwise) sum of 64 squares — validated bit-exact in rounds 1-2
__device__ float sumsq64_np(const float* __restrict__ p) {
    float s[16];
    #pragma unroll
    for (int l = 0; l < 16; ++l) {
        float a0 = fmulr(p[l],      p[l]);
        float a1 = fmulr(p[l + 16], p[l + 16]);
        float a2 = fmulr(p[l + 32], p[l + 32]);
        float a3 = fmulr(p[l + 48], p[l + 48]);
        s[l] = faddr(faddr(a0, a1), faddr(a2, a3));
    }
    #pragma unroll
    for (int len = 8; len >= 1; len >>= 1)
        #pragma unroll
        for (int l = 0; l < len; ++l)
            s[l] = faddr(s[l], s[l + len]);
    return s[0];
}

__device__ __forceinline__ void async_copy16(const void* g, void* l) {
    __builtin_amdgcn_global_load_lds(
        (const __attribute__((address_space(1))) void*)g,
        (__attribute__((address_space(3))) void*)l, 16, 0, 0);
}

// ---------------- prep: W -> swizzled bf16 hi/lo, exact s2, zero accumulators ----
__global__ void vq_prep(const float* __restrict__ W, unsigned short* __restrict__ Whi,
                        unsigned short* __restrict__ Wlo, float* __restrict__ s2g,
                        int* __restrict__ counts, int* __restrict__ gfcount,
                        double* __restrict__ loss_acc) {
    int gid = blockIdx.x * NTH + threadIdx.x;   // 64 blocks -> 16384 threads
    for (int e = gid; e < K_CODES * DIM; e += 16384) {
        float x = W[e];
        unsigned short hi = f2bf(x);
        unsigned short lo = f2bf(__fsub_rn(x, bf2f(hi)));
        int j = e >> 6, k = e & 63;
        int pos = j * 64 + (((k >> 3) ^ (j & 7)) << 3) + (k & 7);
        Whi[pos] = hi; Wlo[pos] = lo;
    }
    if (gid < K_CODES) { s2g[gid] = sumsq64_np(W + gid * 64); counts[gid] = 0; }
    if (gid == 0) { *loss_acc = 0.0; *gfcount = 0; }
}

// ---------------- main: MFMA approx distances, dbuf prefetch, top2, epilogue -----
// 8 waves/block, 2 blocks/CU -> 16 waves/CU. Wave (tg,chd) owns a 32-token x
// 32-code quadrant per chunk: B fragments reused 2x (same LDS traffic as the
// 4-wave version), MFMA identical, occupancy doubled.
__global__ __launch_bounds__(NTHM, 4)
void vq_main(const float* __restrict__ X, const float* __restrict__ W,
             const unsigned short* __restrict__ WhiG, const unsigned short* __restrict__ WloG,
             const float* __restrict__ s2g, float* __restrict__ out,
             double* __restrict__ loss_acc, int* __restrict__ counts,
             int* __restrict__ gfcount, unsigned short* __restrict__ gflist) {
    __shared__ __align__(16) unsigned short xs_hi[TPB * 64];
    __shared__ __align__(16) unsigned short xs_lo[TPB * 64];
    __shared__ __align__(16) unsigned short ws_hi[2][64 * 64];   // dbuf, 8KB each
    __shared__ __align__(16) unsigned short ws_lo[2][64 * 64];
    __shared__ __align__(16) float s2s[K_CODES];
    __shared__ float sm1[2][TPB];        // cross-wave top-2 merge (code halves)
    __shared__ float sm2[2][TPB];
    __shared__ int   si1[2][TPB];
    __shared__ int fidx[TPB];
    __shared__ int flist[TPB];
    __shared__ int fcount, gbaseS;
    __shared__ double lred[8];

    const int tid  = threadIdx.x;
    const int lane = tid & 63, wave = tid >> 6;
    const int quad = lane >> 4, lrow = lane & 15;
    const int tg   = wave & 3;        // token group: 32 tokens
    const int chd  = wave >> 2;       // code half: 32 of each 64-code chunk
    const int t0   = blockIdx.x * TPB;

    if (tid == 0) fcount = 0;

    // prefetch chunk 0 first so it overlaps X staging (16KB: 512 x 16B x {hi,lo})
    {
        const char* gh = (const char*)WhiG;
        const char* gl = (const char*)WloG;
        char* lh = (char*)&ws_hi[0][0] + wave * 1024;
        char* ll = (char*)&ws_lo[0][0] + wave * 1024;
        async_copy16(gh + tid * 16, lh);
        async_copy16(gl + tid * 16, ll);
    }
    // stage s2 (4KB)
    if (tid < 256) *(f32x4*)&s2s[tid * 4] = *(const f32x4*)&s2g[tid * 4];
    // stage X tile as swizzled bf16 hi/lo (1024 groups of 8 floats)
    #pragma unroll
    for (int i = 0; i < 2; ++i) {
        int g = tid + NTHM * i;
        int t = g >> 3, kb = g & 7;
        const float* src = X + (size_t)(t0 + t) * DIM + kb * 8;
        float v[8];
        *(f32x4*)v       = *(const f32x4*)src;
        *(f32x4*)(v + 4) = *(const f32x4*)(src + 4);
        unsigned short h[8], l[8];
        #pragma unroll
        for (int k = 0; k < 8; ++k) {
            h[k] = f2bf(v[k]);
            l[k] = f2bf(__fsub_rn(v[k], bf2f(h[k])));
        }
        int base = t * 64 + ((kb ^ (t & 7)) << 3);
        *(s16x8*)&xs_hi[base] = *(s16x8*)h;
        *(s16x8*)&xs_lo[base] = *(s16x8*)l;
    }
    __syncthreads();   // X/s2 staged (lgkm), chunk-0 prefetch drained (vmcnt)

    // A fragments in registers for the whole kernel: wave owns 32 tokens (2 row-tiles)
    s16x8 a_h0[2], a_h1[2], a_l0[2], a_l1[2];
    #pragma unroll
    for (int rt = 0; rt < 2; ++rt) {
        int tf = tg * 32 + rt * 16 + lrow;
        int sA = tf & 7;
        a_h0[rt] = *(const s16x8*)&xs_hi[tf * 64 + (((0 + quad) ^ sA) << 3)];
        a_h1[rt] = *(const s16x8*)&xs_hi[tf * 64 + (((4 + quad) ^ sA) << 3)];
        a_l0[rt] = *(const s16x8*)&xs_lo[tf * 64 + (((0 + quad) ^ sA) << 3)];
        a_l1[rt] = *(const s16x8*)&xs_lo[tf * 64 + (((4 + quad) ^ sA) << 3)];
    }

    // top-2 of acc (max semantics; d = -2*acc exactly)
    float m1v[8], m2v[8]; int m1i[8];
    #pragma unroll
    for (int ri = 0; ri < 8; ++ri) { m1v[ri] = -3.4e38f; m2v[ri] = -3.4e38f; m1i[ri] = 0x7fffffff; }

    for (int ch = 0; ch < NCH; ++ch) {
        const int buf = ch & 1;
        if (ch < NCH - 1) {   // prefetch next chunk into other buffer (in flight all chunk)
            const char* gh = (const char*)WhiG + (ch + 1) * 8192;
            const char* gl = (const char*)WloG + (ch + 1) * 8192;
            char* lh = (char*)&ws_hi[buf ^ 1][0] + wave * 1024;
            char* ll = (char*)&ws_lo[buf ^ 1][0] + wave * 1024;
            async_copy16(gh + tid * 16, lh);
            async_copy16(gl + tid * 16, ll);
        }
        #pragma unroll
        for (int ct2 = 0; ct2 < 2; ++ct2) {
            int lc = chd * 32 + ct2 * 16 + lrow;  // local code 0..63 (lane's C-column)
            int sB = lrow & 7;
            const unsigned short* bh = &ws_hi[buf][lc * 64];
            const unsigned short* bl = &ws_lo[buf][lc * 64];
            s16x8 b_h0 = *(const s16x8*)&bh[((0 + quad) ^ sB) << 3];
            s16x8 b_h1 = *(const s16x8*)&bh[((4 + quad) ^ sB) << 3];
            s16x8 b_l0 = *(const s16x8*)&bl[((0 + quad) ^ sB) << 3];
            s16x8 b_l1 = *(const s16x8*)&bl[((4 + quad) ^ sB) << 3];
            int jcode = ch * 64 + lc;
            float s2v = s2s[jcode];
            float ainit = fmulr(-0.5f, s2v);
            #pragma unroll
            for (int rt = 0; rt < 2; ++rt) {
                f32x4 acc = {ainit, ainit, ainit, ainit};   // acc = x.w - 0.5*s2
                acc = __builtin_amdgcn_mfma_f32_16x16x32_bf16(a_h0[rt], b_h0, acc, 0, 0, 0);
                acc = __builtin_amdgcn_mfma_f32_16x16x32_bf16(a_h1[rt], b_h1, acc, 0, 0, 0);
                acc = __builtin_amdgcn_mfma_f32_16x16x32_bf16(a_h0[rt], b_l0, acc, 0, 0, 0);
                acc = __builtin_amdgcn_mfma_f32_16x16x32_bf16(a_h1[rt], b_l1, acc, 0, 0, 0);
                acc = __builtin_amdgcn_mfma_f32_16x16x32_bf16(a_l0[rt], b_h0, acc, 0, 0, 0);
                acc = __builtin_amdgcn_mfma_f32_16x16x32_bf16(a_l1[rt], b_h1, acc, 0, 0, 0);
                #pragma unroll
                for (int r = 0; r < 4; ++r) {
                    float a = acc[r];
                    int ri = rt * 4 + r;
                    bool gt = a > m1v[ri];      // strict: keeps earliest code on ties
                    float sec = gt ? m1v[ri] : a;
                    m2v[ri] = fmaxf(m2v[ri], sec);
                    m1v[ri] = gt ? a : m1v[ri];
                    m1i[ri] = gt ? jcode : m1i[ri];
                }
            }
        }
        __syncthreads();   // drains next-chunk prefetch; protects buf reuse
    }

    // butterfly top-2 merge across the 16 lrow lanes (codes disjoint per lane)
    #pragma unroll
    for (int m = 1; m <= 8; m <<= 1) {
        #pragma unroll
        for (int ri = 0; ri < 8; ++ri) {
            float o1v = __shfl_xor(m1v[ri], m, 64);
            int   o1i = __shfl_xor(m1i[ri], m, 64);
            float o2v = __shfl_xor(m2v[ri], m, 64);
            bool take = (o1v > m1v[ri]) || (o1v == m1v[ri] && o1i < m1i[ri]);
            float loser = take ? m1v[ri] : o1v;
            m2v[ri] = fmaxf(fmaxf(m2v[ri], o2v), loser);
            if (take) { m1v[ri] = o1v; m1i[ri] = o1i; }
        }
    }
    // per-half results -> LDS for cross-wave merge (wave pairs share tokens)
    if (lrow == 0) {
        #pragma unroll
        for (int ri = 0; ri < 8; ++ri) {
            int rt = ri >> 2, r = ri & 3;
            int t = tg * 32 + rt * 16 + quad * 4 + r;
            sm1[chd][t] = m1v[ri];
            sm2[chd][t] = m2v[ri];
            si1[chd][t] = m1i[ri];
        }
    }
    __syncthreads();
    if (tid < TPB) {
        int t = tid;
        float a1 = sm1[0][t], b1 = sm1[1][t];
        int   ia = si1[0][t], ib = si1[1][t];
        float a2 = sm2[0][t], b2 = sm2[1][t];
        bool take = (b1 > a1) || (b1 == a1 && ib < ia);
        float w1 = take ? b1 : a1;
        int   wi = take ? ib : ia;
        float loser = take ? a1 : b1;
        float w2 = fmaxf(fmaxf(a2, b2), loser);
        bool fb = __fsub_rn(w1, w2) < HMARGIN;   // == (d2 - d1) < MARGIN
        fidx[t] = fb ? (wi | (int)0x80000000) : wi;
        if (fb) { int p = atomicAdd(&fcount, 1); flist[p] = t; }
    }
    __syncthreads();

    // epilogue for certain (non-fallback) tokens, float4-vectorized
    double lsum = 0.0;
    #pragma unroll
    for (int i = 0; i < 4; ++i) {
        int e4 = tid + NTHM * i;             // 0..2047 float4 groups
        int t = e4 >> 4, d4 = (e4 & 15) * 4;
        int iv = fidx[t];
        if (iv >= 0) {
            f32x4 q = *(const f32x4*)&W[iv * 64 + d4];
            f32x4 x = *(const f32x4*)&X[(size_t)(t0 + t) * 64 + d4];
            *(f32x4*)&out[(size_t)OFF_Q + (size_t)(t0 + t) * 64 + d4] = q;
            #pragma unroll
            for (int c = 0; c < 4; ++c) {
                float df = __fsub_rn(q[c], x[c]);
                lsum += (double)fmulr(df, df);
            }
        }
    }
    #pragma unroll
    for (int off = 32; off >= 1; off >>= 1) lsum += __shfl_down(lsum, off, 64);
    if (lane == 0) lred[wave] = lsum;
    if (tid < TPB) {
        int iv = fidx[tid];
        if (iv >= 0) {
            atomicAdd(&counts[iv], 1);
            out[(size_t)OFF_IDX + t0 + tid] = (float)iv;
        }
    }
    if (tid == 0) gbaseS = atomicAdd(gfcount, fcount);
    __syncthreads();
    if (tid < fcount) gflist[gbaseS + tid] = (unsigned short)(t0 + flist[tid]);
    if (tid == 0)
        atomicAdd(loss_acc, lred[0] + lred[1] + lred[2] + lred[3] +
                            lred[4] + lred[5] + lred[6] + lred[7]);
}

// ---------------- fallback: bit-exact (round-1 arithmetic) rescan, 64 tok/block --
__global__ __launch_bounds__(NTH, 3)
void vq_fallback(const float* __restrict__ X, const float* __restrict__ W,
                 const float* __restrict__ s2g, const int* __restrict__ gfcount,
                 const unsigned short* __restrict__ gflist, float* __restrict__ out,
                 double* __restrict__ loss_acc, int* __restrict__ counts) {
    int count = *gfcount;
    int base = blockIdx.x * 64;
    if (base >= count) return;
    int nt = min(64, count - base);

    __shared__ __align__(16) float xsf[64 * 64];     // 16KB
    __shared__ __align__(16) float wsf[128 * 64];    // 32KB; aliased as u64 red[] later
    __shared__ float s1f[64];
    __shared__ int gidx[64];
    __shared__ double lredf[4];

    const int tid = threadIdx.x;
    const int lane = tid & 63, wave = tid >> 6;
    const int r = tid & 15, c = tid >> 4;   // r: tokens 4r..4r+3, c: codes 8c..8c+7

    // stage X rows of the fallback tokens (padded with token gflist[base])
    #pragma unroll
    for (int i = 0; i < 4; ++i) {
        int idx = tid + NTH * i;            // 0..1023 float4 groups
        int t = idx >> 4, kb = idx & 15;
        int tok = gflist[base + (t < nt ? t : 0)];
        f32x4 v = *(const f32x4*)(X + (size_t)tok * 64 + kb * 4);
        *(f32x4*)&xsf[t * 64 + ((kb ^ ((t >> 2) & 7)) << 2)] = v;
    }
    if (tid < nt) s1f[tid] = sumsq64_np(X + (size_t)gflist[base + tid] * 64);

    float runVal[4]; int runIdx[4];
    #pragma unroll
    for (int i = 0; i < 4; ++i) { runVal[i] = 3.4e38f; runIdx[i] = 0; }

    for (int ch = 0; ch < 8; ++ch) {
        __syncthreads();
        #pragma unroll
        for (int i = 0; i < 8; ++i) {        // stage 128x64 fp32 W chunk, swizzled
            int idx = tid + NTH * i;
            int jl = idx >> 4, kb = idx & 15;
            f32x4 v = *(const f32x4*)(W + (size_t)(ch * 128 + jl) * 64 + kb * 4);
            *(f32x4*)&wsf[jl * 64 + ((kb ^ ((jl >> 3) & 7)) << 2)] = v;
        }
        __syncthreads();

        float acc[4][8];
        #pragma unroll
        for (int i = 0; i < 4; ++i)
            #pragma unroll
            for (int m = 0; m < 8; ++m) acc[i][m] = 0.0f;

        #pragma unroll
        for (int kb = 0; kb < 16; ++kb) {    // exact sequential-k FMA chains
            f32x4 xv[4], wv[8];
            #pragma unroll
            for (int i = 0; i < 4; ++i)
                xv[i] = *(const f32x4*)&xsf[(4 * r + i) * 64 + ((kb ^ (r & 7)) << 2)];
            #pragma unroll
            for (int m = 0; m < 8; ++m)
                wv[m] = *(const f32x4*)&wsf[(8 * c + m) * 64 + ((kb ^ (c & 7)) << 2)];
            #pragma unroll
            for (int i = 0; i < 4; ++i)
                #pragma unroll
                for (int m = 0; m < 8; ++m) {
                    acc[i][m] = __builtin_fmaf(xv[i][0], wv[m][0], acc[i][m]);
                    acc[i][m] = __builtin_fmaf(xv[i][1], wv[m][1], acc[i][m]);
                    acc[i][m] = __builtin_fmaf(xv[i][2], wv[m][2], acc[i][m]);
                    acc[i][m] = __builtin_fmaf(xv[i][3], wv[m][3], acc[i][m]);
                }
        }
        #pragma unroll
        for (int i = 0; i < 4; ++i) {
            float s1v = s1f[4 * r + i];
            #pragma unroll
            for (int m = 0; m < 8; ++m) {
                int jl = 8 * c + m;
                float d = faddr(faddr(s1v, s2g[ch * 128 + jl]), fmulr(-2.0f, acc[i][m]));
                if (d < runVal[i]) { runVal[i] = d; runIdx[i] = ch * 128 + jl; }
            }
        }
    }

    __syncthreads();
    unsigned long long* red = (unsigned long long*)wsf;   // w chunk dead now
    #pragma unroll
    for (int i = 0; i < 4; ++i) {
        unsigned long long pk =
            ((unsigned long long)__float_as_uint(runVal[i]) << 32) |
            (unsigned long long)(unsigned int)runIdx[i];   // d>0 always (s1 dominates)
        red[(4 * r + i) * 16 + c] = pk;
    }
    __syncthreads();
    if (tid < 64) {
        unsigned long long best = red[tid * 16];
        #pragma unroll
        for (int cc = 1; cc < 16; ++cc) {
            unsigned long long v = red[tid * 16 + cc];
            best = (v < best) ? v : best;
        }
        int idx = (int)(best & 0xffffffffu);
        gidx[tid] = idx;
        if (tid < nt) {
            int tok = gflist[base + tid];
            out[(size_t)OFF_IDX + tok] = (float)idx;
            atomicAdd(&counts[idx], 1);
        }
    }
    __syncthreads();
    double lsum = 0.0;
    #pragma unroll
    for (int i = 0; i < 4; ++i) {
        int e4 = tid + NTH * i;              // 0..1023 float4 groups
        int t = e4 >> 4, d4 = (e4 & 15) * 4;
        if (t < nt) {
            int tok = gflist[base + t];
            int idx = gidx[t];
            f32x4 q = *(const f32x4*)&W[idx * 64 + d4];
            f32x4 x = *(const f32x4*)&X[(size_t)tok * 64 + d4];
            *(f32x4*)&out[(size_t)OFF_Q + (size_t)tok * 64 + d4] = q;
            #pragma unroll
            for (int cc = 0; cc < 4; ++cc) {
                float df = __fsub_rn(q[cc], x[cc]);
                lsum += (double)fmulr(df, df);
            }
        }
    }
    #pragma unroll
    for (int off = 32; off >= 1; off >>= 1) lsum += __shfl_down(lsum, off, 64);
    if (lane == 0) lredf[wave] = lsum;
    __syncthreads();
    if (tid == 0) atomicAdd(loss_acc, lredf[0] + lredf[1] + lredf[2] + lredf[3]);
}

// ---------------- final scalars --------------------------------------------------
__global__ void vq_final(const int* __restrict__ counts,
                         const double* __restrict__ loss_acc,
                         float* __restrict__ out) {
    __shared__ double hred[4];
    int tid = threadIdx.x;
    double h = 0.0;
    for (int j = tid; j < K_CODES; j += 256) {
        double p = (double)counts[j] / 65536.0;
        h += p * log(p + 1e-10);
    }
    #pragma unroll
    for (int off = 32; off >= 1; off >>= 1) h += __shfl_down(h, off, 64);
    if ((tid & 63) == 0) hred[tid >> 6] = h;
    __syncthreads();
    if (tid == 0) {
        double H = hred[0] + hred[1] + hred[2] + hred[3];
        out[OFF_PERP] = (float)exp(-H);
        double ls = *loss_acc;
        float Lf = (float)(ls / 4194304.0);
        out[0] = faddr(Lf, fmulr(0.25f, Lf));
    }
}

extern "C" void kernel_launch(void* const* d_in, const int* in_sizes, int n_in,
                              void* d_out, int out_size, void* d_ws, size_t ws_size,
                              hipStream_t stream) {
    const float* X = (const float*)d_in[0];
    const float* W = (const float*)d_in[1];
    float* out = (float*)d_out;
    char* ws = (char*)d_ws;
    double* loss_acc = (double*)(ws + WS_LOSS);
    int* gfcount = (int*)(ws + WS_FCNT);
    int* counts = (int*)(ws + WS_COUNTS);
    unsigned short* Whi = (unsigned short*)(ws + WS_WHI);
    unsigned short* Wlo = (unsigned short*)(ws + WS_WLO);
    float* s2g = (float*)(ws + WS_S2);
    unsigned short* gflist = (unsigned short*)(ws + WS_FLIST);

    vq_prep<<<64, NTH, 0, stream>>>(W, Whi, Wlo, s2g, counts, gfcount, loss_acc);
    vq_main<<<N_TOKENS / TPB, NTHM, 0, stream>>>(X, W, Whi, Wlo, s2g, out,
                                                 loss_acc, counts, gfcount, gflist);
    vq_fallback<<<N_TOKENS / 64, NTH, 0, stream>>>(X, W, s2g, gfcount, gflist,
                                                   out, loss_acc, counts);
    vq_final<<<1, NTH, 0, stream>>>(counts, loss_acc, out);
}